// Round 5
// baseline (504.997 us; speedup 1.0000x reference)
//
#include <hip/hip_runtime.h>
#include <cstdint>
#include <cstddef>

#define N 8192
#define D 128
#define KNN 20
#define NC 10
#define LCAP 1280          // Cantelli bound at z=2.45: N/(1+z^2)=1170 < 1280
#define ZTH 2.45f
constexpr float EPS = 1e-10f;

typedef __attribute__((ext_vector_type(8))) short short8;
typedef __attribute__((ext_vector_type(4))) float f32x4;

__device__ inline unsigned short f32_to_bf16_rne(float x) {
    unsigned u = __float_as_uint(x);
    unsigned r = u + 0x7FFFu + ((u >> 16) & 1u);
    return (unsigned short)(r >> 16);
}
__device__ inline float bf16_to_f32(unsigned short h) {
    return __uint_as_float((unsigned)h << 16);
}

// ---------------- K1: squared norms (exact fp32) ----------------
__global__ void k_sqnorm(const float* __restrict__ X, float* __restrict__ sq) {
    int row = blockIdx.x;
    int lane = threadIdx.x;
    const float2* X2 = (const float2*)(X + (size_t)row * D);
    float2 a = X2[lane];
    float s = a.x * a.x + a.y * a.y;
    #pragma unroll
    for (int off = 32; off; off >>= 1) s += __shfl_down(s, off, 64);
    if (lane == 0) sq[row] = s;
}

// ---------------- K2: split X into bf16 hi + lo ----------------
__global__ void k_split(const float* __restrict__ X, unsigned short* __restrict__ Xhi,
                        unsigned short* __restrict__ Xlo) {
    int i = blockIdx.x * 256 + threadIdx.x;
    const float4* X4 = (const float4*)X;
    float4 x = X4[i];
    unsigned short h[4], l[4];
    float xs[4] = {x.x, x.y, x.z, x.w};
    #pragma unroll
    for (int q = 0; q < 4; ++q) {
        h[q] = f32_to_bf16_rne(xs[q]);
        l[q] = f32_to_bf16_rne(xs[q] - bf16_to_f32(h[q]));
    }
    *(ushort4*)&Xhi[(size_t)i * 4] = make_ushort4(h[0], h[1], h[2], h[3]);
    *(ushort4*)&Xlo[(size_t)i * 4] = make_ushort4(l[0], l[1], l[2], l[3]);
}

// ---------------- K3: column sums for closed-form stats ----------------
__global__ void k_colstats(const float* __restrict__ X, const float* __restrict__ sq,
                           float* __restrict__ xbsum, float* __restrict__ wvsum) {
    __shared__ float redx[256], redw[256];
    int t = threadIdx.x;
    int c = t & 127, h = t >> 7;
    int j0 = blockIdx.x * 128;
    float sx = 0.f, sw = 0.f;
    for (int it = 0; it < 64; ++it) {
        int j = j0 + h + 2 * it;
        float x = X[(size_t)j * D + c];
        sx += x;
        sw = fmaf(x, sq[j], sw);
    }
    redx[t] = sx; redw[t] = sw; __syncthreads();
    if (t < 128) {
        atomicAdd(&xbsum[t], redx[t] + redx[t + 128]);
        atomicAdd(&wvsum[t], redw[t] + redw[t + 128]);
    }
}

// ---------------- K4: scalar stats of sq ----------------
__global__ void k_sqred(const float* __restrict__ sq, float* __restrict__ scal) {
    __shared__ float r1[256], r2[256];
    int t = threadIdx.x;
    float s1 = 0.f, s2 = 0.f;
    for (int i = t; i < N; i += 256) { float x = sq[i]; s1 += x; s2 = fmaf(x, x, s2); }
    r1[t] = s1; r2[t] = s2; __syncthreads();
    for (int s = 128; s; s >>= 1) {
        if (t < s) { r1[t] += r1[t + s]; r2[t] += r2[t + s]; }
        __syncthreads();
    }
    if (t == 0) { float m = r1[0] / N; scal[0] = m; scal[1] = r2[0] / N - m * m; }
}

// ---------------- K5: partial M = X^T X ----------------
__global__ __launch_bounds__(256) void k_Mpart(const float* __restrict__ X,
                                               float* __restrict__ Mpart) {
    __shared__ float Xs[64 * 132];
    int t = threadIdx.x;
    int j0 = blockIdx.x * 64;
    const float4* X4 = (const float4*)X;
    #pragma unroll
    for (int p = 0; p < 8; ++p) {
        int u = t + 256 * p, r = u >> 5, kq = u & 31;
        *(float4*)&Xs[r * 132 + kq * 4] = X4[(size_t)(j0 + r) * 32 + kq];
    }
    __syncthreads();
    int a0 = (t & 15) * 8, b0 = (t >> 4) * 8;
    float acc[8][8] = {};
    for (int j = 0; j < 64; ++j) {
        float av[8], bv[8];
        *(float4*)&av[0] = *(const float4*)&Xs[j * 132 + a0];
        *(float4*)&av[4] = *(const float4*)&Xs[j * 132 + a0 + 4];
        *(float4*)&bv[0] = *(const float4*)&Xs[j * 132 + b0];
        *(float4*)&bv[4] = *(const float4*)&Xs[j * 132 + b0 + 4];
        #pragma unroll
        for (int i = 0; i < 8; ++i)
            #pragma unroll
            for (int k = 0; k < 8; ++k) acc[i][k] = fmaf(av[i], bv[k], acc[i][k]);
    }
    float* outp = Mpart + (size_t)blockIdx.x * 16384;
    #pragma unroll
    for (int i = 0; i < 8; ++i) {
        *(float4*)&outp[(a0 + i) * 128 + b0]     = *(float4*)&acc[i][0];
        *(float4*)&outp[(a0 + i) * 128 + b0 + 4] = *(float4*)&acc[i][4];
    }
}

__global__ void k_Mred(const float* __restrict__ Mpart, float* __restrict__ M) {
    int e = blockIdx.x * 256 + threadIdx.x;
    float s = 0.f;
    for (int b = 0; b < 128; ++b) s += Mpart[(size_t)b * 16384 + e];
    M[e] = s;
}

// ---------------- K6: Y = X * M ----------------
__global__ __launch_bounds__(256) void k_gemmY(const float* __restrict__ X,
                                               const float* __restrict__ Mm,
                                               float* __restrict__ Y) {
    __shared__ float As[64 * 68];
    __shared__ float Bs[64 * 68];
    int t = threadIdx.x, tx = t & 15, ty = t >> 4;
    int rowTile = blockIdx.y * 64, colTile = blockIdx.x * 64;
    const float4* X4 = (const float4*)X;
    const float4* M4 = (const float4*)Mm;
    float acc[4][4] = {};
    #pragma unroll
    for (int s = 0; s < 2; ++s) {
        __syncthreads();
        #pragma unroll
        for (int p = 0; p < 4; ++p) {
            int u = t + 256 * p, r = u >> 4, k4 = u & 15;
            *(float4*)&As[r * 68 + k4 * 4] = X4[(size_t)(rowTile + r) * 32 + s * 16 + k4];
            *(float4*)&Bs[r * 68 + k4 * 4] = M4[(size_t)(colTile + r) * 32 + s * 16 + k4];
        }
        __syncthreads();
        #pragma unroll
        for (int k4 = 0; k4 < 16; ++k4) {
            float4 a4[4], b4[4];
            #pragma unroll
            for (int q = 0; q < 4; ++q) a4[q] = *(const float4*)&As[(ty + 16 * q) * 68 + k4 * 4];
            #pragma unroll
            for (int q = 0; q < 4; ++q) b4[q] = *(const float4*)&Bs[(tx + 16 * q) * 68 + k4 * 4];
            #pragma unroll
            for (int i = 0; i < 4; ++i)
                #pragma unroll
                for (int j = 0; j < 4; ++j) {
                    acc[i][j] = fmaf(a4[i].x, b4[j].x, acc[i][j]);
                    acc[i][j] = fmaf(a4[i].y, b4[j].y, acc[i][j]);
                    acc[i][j] = fmaf(a4[i].z, b4[j].z, acc[i][j]);
                    acc[i][j] = fmaf(a4[i].w, b4[j].w, acc[i][j]);
                }
        }
    }
    #pragma unroll
    for (int i = 0; i < 4; ++i)
        #pragma unroll
        for (int j = 0; j < 4; ++j)
            Y[(size_t)(rowTile + ty + 16 * i) * 128 + colTile + tx + 16 * j] = acc[i][j];
}

// ---------------- K7: per-row threshold T = mu - z*sigma (closed form, exact fp32) ----
__global__ __launch_bounds__(256) void k_thresh(const float* __restrict__ X,
        const float* __restrict__ Y, const float* __restrict__ sqn,
        const float* __restrict__ xbsum, const float* __restrict__ wvsum,
        const float* __restrict__ scal, float* __restrict__ T) {
    int t = threadIdx.x;
    int row = blockIdx.x * 4 + (t >> 6);
    int lane = t & 63;
    const float2* X2 = (const float2*)X;
    const float2* Y2 = (const float2*)Y;
    const float2* B2 = (const float2*)xbsum;
    const float2* W2 = (const float2*)wvsum;
    float2 x = X2[(size_t)row * 64 + lane];
    float2 y = Y2[(size_t)row * 64 + lane];
    float2 b = B2[lane];
    float2 w = W2[lane];
    float pa = x.x * b.x + x.y * b.y;
    float pc = x.x * w.x + x.y * w.y;
    float pq = x.x * y.x + x.y * y.y;
    #pragma unroll
    for (int off = 32; off; off >>= 1) {
        pa += __shfl_down(pa, off, 64);
        pc += __shfl_down(pc, off, 64);
        pq += __shfl_down(pq, off, 64);
    }
    if (lane == 0) {
        const float inv = 1.f / N;
        float a = pa * inv, c = pc * inv, q = pq * inv;
        float m_sq = scal[0], vs = scal[1];
        float mu  = sqn[row] + m_sq - 2.f * a;
        float var = vs + 4.f * (q - a * a) - 4.f * (c - m_sq * a);
        T[row] = mu - ZTH * sqrtf(fmaxf(var, 0.f));
    }
}

// ---------------- K8: fused split-bf16 MFMA distance + threshold push ----------------
// Block owns 64 rows exclusively (A hi/lo in registers); streams 64-col B tiles
// from L2 via LDS (XOR chunk swizzle -> conflict-free ds_read_b128).
// grid = (4 col-quarters, 128 row-strips); survivors -> per-row global lists.
__global__ __launch_bounds__(256, 2) void k_fused(
        const unsigned short* __restrict__ Xhi, const unsigned short* __restrict__ Xlo,
        const float* __restrict__ sqn, const float* __restrict__ T,
        unsigned long long* __restrict__ list, int* __restrict__ cntg) {
    __shared__ uint4 sBhi[64 * 16];
    __shared__ uint4 sBlo[64 * 16];

    const int t    = threadIdx.x;
    const int lane = t & 63;
    const int w    = t >> 6;          // wave id = col-frag id (16 cols each)
    const int lrow = lane & 15;
    const int lkg  = lane >> 4;       // k-group / row-quad in C layout

    const int rbase    = blockIdx.y * 64;
    const int colbase0 = blockIdx.x * 2048;

    // A fragments (hi+lo) for this block's 64 rows, held in registers for the
    // whole kernel: 4 row-frags x 4 k-chunks x 16B = 128 VGPRs.
    short8 ahi[4][4], alo[4][4];
    #pragma unroll
    for (int i = 0; i < 4; ++i)
        #pragma unroll
        for (int kc = 0; kc < 4; ++kc) {
            size_t g = (size_t)(rbase + (i << 4) + lrow) * 128 + kc * 32 + lkg * 8;
            ahi[i][kc] = *(const short8*)&Xhi[g];
            alo[i][kc] = *(const short8*)&Xlo[g];
        }
    // per-lane epilogue rows: rbase + 16i + 4*lkg + q
    float sa[4][4], Ta[4][4];
    #pragma unroll
    for (int i = 0; i < 4; ++i)
        #pragma unroll
        for (int q = 0; q < 4; ++q) {
            int r = rbase + (i << 4) + (lkg << 2) + q;
            sa[i][q] = sqn[r];
            Ta[i][q] = T[r];
        }

    for (int it = 0; it < 32; ++it) {
        const int colbase = colbase0 + it * 64;
        __syncthreads();
        // stage B tile: 64 cols x 128 k, hi+lo, chunk-XOR swizzle
        #pragma unroll
        for (int p = 0; p < 4; ++p) {
            int u = t + 256 * p, r = u >> 4, c = u & 15;
            int phys = r * 16 + (c ^ (r & 7));
            size_t g = (size_t)(colbase + r) * 128 + c * 8;
            sBhi[phys] = *(const uint4*)&Xhi[g];
            sBlo[phys] = *(const uint4*)&Xlo[g];
        }
        __syncthreads();

        const int jj = (w << 4) | lrow;            // this lane's B row (col) in tile
        short8 bhi[4], blo[4];
        #pragma unroll
        for (int kc = 0; kc < 4; ++kc) {
            int phys = jj * 16 + ((kc * 4 + lkg) ^ (jj & 7));
            bhi[kc] = *(const short8*)&sBhi[phys];
            blo[kc] = *(const short8*)&sBlo[phys];
        }

        f32x4 acc[4];
        #pragma unroll
        for (int i = 0; i < 4; ++i) acc[i] = (f32x4){0.f, 0.f, 0.f, 0.f};
        #pragma unroll
        for (int kc = 0; kc < 4; ++kc)
            #pragma unroll
            for (int i = 0; i < 4; ++i) {
                acc[i] = __builtin_amdgcn_mfma_f32_16x16x32_bf16(ahi[i][kc], bhi[kc], acc[i], 0, 0, 0);
                acc[i] = __builtin_amdgcn_mfma_f32_16x16x32_bf16(ahi[i][kc], blo[kc], acc[i], 0, 0, 0);
                acc[i] = __builtin_amdgcn_mfma_f32_16x16x32_bf16(alo[i][kc], bhi[kc], acc[i], 0, 0, 0);
            }

        // epilogue: C layout col=lane&15 (this wave's 16 cols), row=4*lkg+q
        const int cola = colbase + (w << 4) + lrow;
        const float sb = sqn[cola];
        #pragma unroll
        for (int i = 0; i < 4; ++i)
            #pragma unroll
            for (int q = 0; q < 4; ++q) {
                float d2v = fmaxf(fmaf(-2.f, acc[i][q], sa[i][q] + sb), 0.f);
                if (d2v < Ta[i][q]) {
                    int grow = rbase + (i << 4) + (lkg << 2) + q;
                    int pos = atomicAdd(&cntg[grow], 1);
                    if (pos < LCAP)
                        list[(size_t)grow * LCAP + pos] =
                            ((unsigned long long)__float_as_uint(d2v) << 14) |
                            (unsigned long long)(cola + 1);
                }
            }
    }
}

// ---------------- K9: exact top-20 from candidate list (one wave per row) ----------
__global__ void k_top(const unsigned long long* __restrict__ list,
                      const int* __restrict__ cntg, int* __restrict__ knn_idx,
                      float* __restrict__ density, int* __restrict__ flagv) {
    int row = blockIdx.x, t = threadIdx.x;
    int cnt = cntg[row];
    bool bad = (cnt < KNN) || (cnt > LCAP);
    if (t == 0) flagv[row] = bad ? 1 : 0;
    if (bad) return;
    const unsigned long long* Lp = list + (size_t)row * LCAP;
    unsigned long long last = 0ull;
    float sumd = 0.f;
    for (int r = 0; r < KNN; ++r) {
        unsigned long long m = ~0ull;
        for (int s = t; s < cnt; s += 64) {
            unsigned long long k = Lp[s];
            if (k > last && k < m) m = k;
        }
        #pragma unroll
        for (int off = 32; off; off >>= 1) {
            unsigned long long o = __shfl_down(m, off, 64);
            if (o < m) m = o;
        }
        m = __shfl(m, 0, 64);
        last = m;
        if (t == 0) {
            int j = (int)(m & 16383ull) - 1;
            if (j < 0) j = 0; if (j >= N) j = N - 1;
            knn_idx[(size_t)row * KNN + r] = j;
            sumd += sqrtf(__uint_as_float((unsigned)(m >> 14)));
        }
    }
    if (t == 0) density[row] = 1.f / (sumd * (1.f / KNN) + EPS);
}

// ---------------- K10: exact fp32 fallback for flagged rows ----------------
__global__ __launch_bounds__(256) void k_fb(const float* __restrict__ X,
        const float* __restrict__ sqn, const int* __restrict__ flagv,
        int* __restrict__ knn_idx, float* __restrict__ density) {
    int row = blockIdx.x;
    if (flagv[row] == 0) return;
    __shared__ float xi[128];
    __shared__ float drow[N];
    __shared__ float redf1[256], redf2[256];
    __shared__ int redi[256];
    __shared__ unsigned long long lst[2048];
    __shared__ int lc;
    int t = threadIdx.x;
    if (t < 32) *(float4*)&xi[t * 4] = ((const float4*)X)[(size_t)row * 32 + t];
    __syncthreads();
    float sqi = sqn[row];
    for (int p = 0; p < 32; ++p) {
        int j = t + 256 * p;
        const float4* xj = (const float4*)X + (size_t)j * 32;
        float dot = 0.f;
        #pragma unroll
        for (int d4 = 0; d4 < 32; ++d4) {
            float4 a = xj[d4];
            float4 b = *(const float4*)&xi[d4 * 4];
            dot = fmaf(a.x, b.x, dot); dot = fmaf(a.y, b.y, dot);
            dot = fmaf(a.z, b.z, dot); dot = fmaf(a.w, b.w, dot);
        }
        drow[j] = fmaxf(sqi + sqn[j] - 2.f * dot, 0.f);
    }
    __syncthreads();
    float s1 = 0.f, s2 = 0.f;
    for (int p = 0; p < 32; ++p) { float x = drow[t + 256 * p]; s1 += x; s2 = fmaf(x, x, s2); }
    redf1[t] = s1; redf2[t] = s2; __syncthreads();
    for (int s = 128; s; s >>= 1) {
        if (t < s) { redf1[t] += redf1[t + s]; redf2[t] += redf2[t + s]; }
        __syncthreads();
    }
    float mu = redf1[0] * (1.f / N);
    float var = redf2[0] * (1.f / N) - mu * mu;
    float sigma = sqrtf(fmaxf(var, 0.f)) + 1e-6f;
    __syncthreads();
    float Tlo = 0.f, Thi = mu, T = mu - 2.2f * sigma;
    if (T <= 0.f) T = 0.5f * (Tlo + Thi);
    for (int itx = 0; itx < 32; ++itx) {
        int c = 0;
        for (int p = 0; p < 32; ++p) c += (drow[t + 256 * p] < T) ? 1 : 0;
        redi[t] = c; __syncthreads();
        for (int s = 128; s; s >>= 1) {
            if (t < s) redi[t] += redi[t + s];
            __syncthreads();
        }
        int n = redi[0]; __syncthreads();
        if (n >= KNN && n <= 2048) break;
        if (n < KNN) Tlo = T; else Thi = T;
        T = 0.5f * (Tlo + Thi);
    }
    if (t == 0) lc = 0;
    __syncthreads();
    for (int p = 0; p < 32; ++p) {
        int j = t + 256 * p;
        float x = drow[j];
        if (x < T) {
            int pos = atomicAdd(&lc, 1);
            if (pos < 2048)
                lst[pos] = ((unsigned long long)__float_as_uint(x) << 14) |
                           (unsigned long long)(j + 1);
        }
    }
    __syncthreads();
    int n = min(lc, 2048);
    if (t < 64) {
        unsigned long long last = 0ull; float sumd = 0.f;
        for (int r = 0; r < KNN; ++r) {
            unsigned long long m = ~0ull;
            for (int s = t; s < n; s += 64) {
                unsigned long long k = lst[s];
                if (k > last && k < m) m = k;
            }
            #pragma unroll
            for (int off = 32; off; off >>= 1) {
                unsigned long long o = __shfl_down(m, off, 64);
                if (o < m) m = o;
            }
            m = __shfl(m, 0, 64);
            last = m;
            if (t == 0) {
                int j = (int)(m & 16383ull) - 1;
                if (j < 0) j = 0; if (j >= N) j = N - 1;
                knn_idx[(size_t)row * KNN + r] = j;
                sumd += sqrtf(__uint_as_float((unsigned)(m >> 14)));
            }
        }
        if (t == 0) density[row] = 1.f / (sumd * (1.f / KNN) + EPS);
    }
}

// ---------------- K11: scatter knn + rnn (deduped) contributions ----------------
__global__ void k_scatter(const int* __restrict__ knn_idx, const float* __restrict__ density,
                          float* __restrict__ numer, float* __restrict__ cnt) {
    int p = blockIdx.x * 256 + threadIdx.x;
    if (p >= N * KNN) return;
    int i = p / KNN;
    int j = knn_idx[p];
    atomicAdd(&numer[i], density[j]);
    atomicAdd(&cnt[i], 1.f);
    bool found = false;
    const int* kj = knn_idx + (size_t)j * KNN;
    #pragma unroll
    for (int m = 0; m < KNN; ++m) found |= (kj[m] == i);
    if (!found) {
        atomicAdd(&numer[j], density[i]);
        atomicAdd(&cnt[j], 1.f);
    }
}

// ---------------- K12: scores, flags, class preds ----------------
__global__ void k_final(const float* __restrict__ density, const float* __restrict__ numer,
                        const float* __restrict__ cnt, const float* __restrict__ logits,
                        float* __restrict__ out) {
    int i = blockIdx.x * 256 + threadIdx.x;
    if (i >= N) return;
    float c     = fmaxf(cnt[i], 1.f);
    float avg   = numer[i] / c;
    float score = -(density[i] / (avg + EPS));
    out[i] = score;
    bool flag = score < -0.5f;
    out[N + i] = flag ? 1.f : 0.f;
    const float* lg = logits + (size_t)i * NC;
    float best = lg[0]; int bi = 0;
    #pragma unroll
    for (int k = 1; k < NC; ++k) { float x = lg[k]; if (x > best) { best = x; bi = k; } }
    out[2 * N + i] = flag ? -1.f : (float)bi;
}

extern "C" void kernel_launch(void* const* d_in, const int* in_sizes, int n_in,
                              void* d_out, int out_size, void* d_ws, size_t ws_size,
                              hipStream_t stream) {
    const float* X      = (const float*)d_in[0];
    const float* logits = (const float*)d_in[1];
    float* out = (float*)d_out;

    char* w = (char*)d_ws;
    auto alloc = [&](size_t bytes) { char* p = w; w += (bytes + 255) & ~(size_t)255; return p; };
    float* sq      = (float*)alloc((size_t)N * 4);
    float* T       = (float*)alloc((size_t)N * 4);
    float* density = (float*)alloc((size_t)N * 4);
    float* numer   = (float*)alloc((size_t)N * 4);
    float* cntb    = (float*)alloc((size_t)N * 4);
    int*   flagv   = (int*)alloc((size_t)N * 4);
    int*   cntg    = (int*)alloc((size_t)N * 4);
    int*   knn     = (int*)alloc((size_t)N * KNN * 4);
    unsigned short* Xhi = (unsigned short*)alloc((size_t)N * D * 2);
    unsigned short* Xlo = (unsigned short*)alloc((size_t)N * D * 2);
    float* xbsum   = (float*)alloc(512);
    float* wvsum   = (float*)alloc(512);
    float* scal    = (float*)alloc(256);
    float* M       = (float*)alloc(65536);
    float* Mpart   = (float*)alloc((size_t)128 * 16384 * 4);
    float* Y       = (float*)alloc((size_t)N * 128 * 4);
    unsigned long long* list = (unsigned long long*)alloc((size_t)N * LCAP * 8);

    (void)hipMemsetAsync(cntg,  0, (size_t)N * 4, stream);
    (void)hipMemsetAsync(numer, 0, (size_t)N * 4, stream);
    (void)hipMemsetAsync(cntb,  0, (size_t)N * 4, stream);
    (void)hipMemsetAsync(xbsum, 0, 512, stream);
    (void)hipMemsetAsync(wvsum, 0, 512, stream);

    k_sqnorm  <<<N, 64, 0, stream>>>(X, sq);
    k_split   <<<(N * D / 4 + 255) / 256, 256, 0, stream>>>(X, Xhi, Xlo);
    k_colstats<<<64, 256, 0, stream>>>(X, sq, xbsum, wvsum);
    k_sqred   <<<1, 256, 0, stream>>>(sq, scal);
    k_Mpart   <<<128, 256, 0, stream>>>(X, Mpart);
    k_Mred    <<<64, 256, 0, stream>>>(Mpart, M);
    k_gemmY   <<<dim3(2, 128), 256, 0, stream>>>(X, M, Y);
    k_thresh  <<<N / 4, 256, 0, stream>>>(X, Y, sq, xbsum, wvsum, scal, T);
    k_fused   <<<dim3(4, 128), 256, 0, stream>>>(Xhi, Xlo, sq, T, list, cntg);
    k_top     <<<N, 64, 0, stream>>>(list, cntg, knn, density, flagv);
    k_fb      <<<N, 256, 0, stream>>>(X, sq, flagv, knn, density);
    k_scatter <<<(N * KNN + 255) / 256, 256, 0, stream>>>(knn, density, numer, cntb);
    k_final   <<<(N + 255) / 256, 256, 0, stream>>>(density, numer, cntb, logits, out);
}

// Round 6
// 412.781 us; speedup vs baseline: 1.2234x; 1.2234x over previous
//
#include <hip/hip_runtime.h>
#include <cstdint>
#include <cstddef>

#define N 8192
#define D 128
#define KNN 20
#define NC 10
#define LCAP 1280          // Cantelli bound at z=2.45: N/(1+z^2)=1170 < 1280
#define ZTH 2.45f
#define FBMAX 512          // max materialized fallback rows (16 MB scratch)
constexpr float EPS = 1e-10f;

typedef __attribute__((ext_vector_type(8))) short short8;
typedef __attribute__((ext_vector_type(4))) float f32x4;

__device__ inline unsigned short f32_to_bf16_rne(float x) {
    unsigned u = __float_as_uint(x);
    unsigned r = u + 0x7FFFu + ((u >> 16) & 1u);
    return (unsigned short)(r >> 16);
}
__device__ inline float bf16_to_f32(unsigned short h) {
    return __uint_as_float((unsigned)h << 16);
}

// ---------------- K1: squared norms + bf16 hi/lo split (one X pass) ----------------
__global__ void k_sqsplit(const float* __restrict__ X, float* __restrict__ sq,
                          unsigned short* __restrict__ Xhi, unsigned short* __restrict__ Xlo) {
    int row = blockIdx.x;
    int lane = threadIdx.x;                      // 64 lanes
    const float2* X2 = (const float2*)(X + (size_t)row * D);
    float2 a = X2[lane];
    float s = a.x * a.x + a.y * a.y;
    unsigned short h0 = f32_to_bf16_rne(a.x);
    unsigned short l0 = f32_to_bf16_rne(a.x - bf16_to_f32(h0));
    unsigned short h1 = f32_to_bf16_rne(a.y);
    unsigned short l1 = f32_to_bf16_rne(a.y - bf16_to_f32(h1));
    *(ushort2*)&Xhi[(size_t)row * D + lane * 2] = make_ushort2(h0, h1);
    *(ushort2*)&Xlo[(size_t)row * D + lane * 2] = make_ushort2(l0, l1);
    #pragma unroll
    for (int off = 32; off; off >>= 1) s += __shfl_down(s, off, 64);
    if (lane == 0) sq[row] = s;
}

// ---------------- K2: column sums + scalar sq stats ----------------
__global__ void k_colstats(const float* __restrict__ X, const float* __restrict__ sq,
                           float* __restrict__ xbsum, float* __restrict__ wvsum,
                           float* __restrict__ scal_s) {
    __shared__ float redx[256], redw[256];
    int t = threadIdx.x;
    int c = t & 127, h = t >> 7;
    int j0 = blockIdx.x * 128;
    float sx = 0.f, sw = 0.f, ss1 = 0.f, ss2 = 0.f;
    for (int it = 0; it < 64; ++it) {
        int j = j0 + h + 2 * it;
        float x = X[(size_t)j * D + c];
        float sj = sq[j];
        sx += x;
        sw = fmaf(x, sj, sw);
        if (c == 0) { ss1 += sj; ss2 = fmaf(sj, sj, ss2); }
    }
    redx[t] = sx; redw[t] = sw; __syncthreads();
    if (t < 128) {
        atomicAdd(&xbsum[t], redx[t] + redx[t + 128]);
        atomicAdd(&wvsum[t], redw[t] + redw[t + 128]);
    }
    if (c == 0) {
        atomicAdd(&scal_s[0], ss1);
        atomicAdd(&scal_s[1], ss2);
    }
}

// ---------------- K3: partial M = X^T X ----------------
__global__ __launch_bounds__(256) void k_Mpart(const float* __restrict__ X,
                                               float* __restrict__ Mpart) {
    __shared__ float Xs[64 * 132];
    int t = threadIdx.x;
    int j0 = blockIdx.x * 64;
    const float4* X4 = (const float4*)X;
    #pragma unroll
    for (int p = 0; p < 8; ++p) {
        int u = t + 256 * p, r = u >> 5, kq = u & 31;
        *(float4*)&Xs[r * 132 + kq * 4] = X4[(size_t)(j0 + r) * 32 + kq];
    }
    __syncthreads();
    int a0 = (t & 15) * 8, b0 = (t >> 4) * 8;
    float acc[8][8] = {};
    for (int j = 0; j < 64; ++j) {
        float av[8], bv[8];
        *(float4*)&av[0] = *(const float4*)&Xs[j * 132 + a0];
        *(float4*)&av[4] = *(const float4*)&Xs[j * 132 + a0 + 4];
        *(float4*)&bv[0] = *(const float4*)&Xs[j * 132 + b0];
        *(float4*)&bv[4] = *(const float4*)&Xs[j * 132 + b0 + 4];
        #pragma unroll
        for (int i = 0; i < 8; ++i)
            #pragma unroll
            for (int k = 0; k < 8; ++k) acc[i][k] = fmaf(av[i], bv[k], acc[i][k]);
    }
    float* outp = Mpart + (size_t)blockIdx.x * 16384;
    #pragma unroll
    for (int i = 0; i < 8; ++i) {
        *(float4*)&outp[(a0 + i) * 128 + b0]     = *(float4*)&acc[i][0];
        *(float4*)&outp[(a0 + i) * 128 + b0 + 4] = *(float4*)&acc[i][4];
    }
}

__global__ void k_Mred(const float* __restrict__ Mpart, float* __restrict__ M) {
    int e = blockIdx.x * 256 + threadIdx.x;
    float s = 0.f;
    for (int b = 0; b < 128; ++b) s += Mpart[(size_t)b * 16384 + e];
    M[e] = s;
}

// ---------------- K4: Y = X * M ----------------
__global__ __launch_bounds__(256) void k_gemmY(const float* __restrict__ X,
                                               const float* __restrict__ Mm,
                                               float* __restrict__ Y) {
    __shared__ float As[64 * 68];
    __shared__ float Bs[64 * 68];
    int t = threadIdx.x, tx = t & 15, ty = t >> 4;
    int rowTile = blockIdx.y * 64, colTile = blockIdx.x * 64;
    const float4* X4 = (const float4*)X;
    const float4* M4 = (const float4*)Mm;
    float acc[4][4] = {};
    #pragma unroll
    for (int s = 0; s < 2; ++s) {
        __syncthreads();
        #pragma unroll
        for (int p = 0; p < 4; ++p) {
            int u = t + 256 * p, r = u >> 4, k4 = u & 15;
            *(float4*)&As[r * 68 + k4 * 4] = X4[(size_t)(rowTile + r) * 32 + s * 16 + k4];
            *(float4*)&Bs[r * 68 + k4 * 4] = M4[(size_t)(colTile + r) * 32 + s * 16 + k4];
        }
        __syncthreads();
        #pragma unroll
        for (int k4 = 0; k4 < 16; ++k4) {
            float4 a4[4], b4[4];
            #pragma unroll
            for (int q = 0; q < 4; ++q) a4[q] = *(const float4*)&As[(ty + 16 * q) * 68 + k4 * 4];
            #pragma unroll
            for (int q = 0; q < 4; ++q) b4[q] = *(const float4*)&Bs[(tx + 16 * q) * 68 + k4 * 4];
            #pragma unroll
            for (int i = 0; i < 4; ++i)
                #pragma unroll
                for (int j = 0; j < 4; ++j) {
                    acc[i][j] = fmaf(a4[i].x, b4[j].x, acc[i][j]);
                    acc[i][j] = fmaf(a4[i].y, b4[j].y, acc[i][j]);
                    acc[i][j] = fmaf(a4[i].z, b4[j].z, acc[i][j]);
                    acc[i][j] = fmaf(a4[i].w, b4[j].w, acc[i][j]);
                }
        }
    }
    #pragma unroll
    for (int i = 0; i < 4; ++i)
        #pragma unroll
        for (int j = 0; j < 4; ++j)
            Y[(size_t)(rowTile + ty + 16 * i) * 128 + colTile + tx + 16 * j] = acc[i][j];
}

// ---------------- K5: per-row threshold T = mu - z*sigma (closed form) ----------
__global__ __launch_bounds__(256) void k_thresh(const float* __restrict__ X,
        const float* __restrict__ Y, const float* __restrict__ sqn,
        const float* __restrict__ xbsum, const float* __restrict__ wvsum,
        const float* __restrict__ scal_s, float* __restrict__ T) {
    int t = threadIdx.x;
    int row = blockIdx.x * 4 + (t >> 6);
    int lane = t & 63;
    const float2* X2 = (const float2*)X;
    const float2* Y2 = (const float2*)Y;
    const float2* B2 = (const float2*)xbsum;
    const float2* W2 = (const float2*)wvsum;
    float2 x = X2[(size_t)row * 64 + lane];
    float2 y = Y2[(size_t)row * 64 + lane];
    float2 b = B2[lane];
    float2 w = W2[lane];
    float pa = x.x * b.x + x.y * b.y;
    float pc = x.x * w.x + x.y * w.y;
    float pq = x.x * y.x + x.y * y.y;
    #pragma unroll
    for (int off = 32; off; off >>= 1) {
        pa += __shfl_down(pa, off, 64);
        pc += __shfl_down(pc, off, 64);
        pq += __shfl_down(pq, off, 64);
    }
    if (lane == 0) {
        const float inv = 1.f / N;
        float a = pa * inv, c = pc * inv, q = pq * inv;
        float m_sq = scal_s[0] * inv;
        float vs   = scal_s[1] * inv - m_sq * m_sq;
        float mu  = sqn[row] + m_sq - 2.f * a;
        float var = vs + 4.f * (q - a * a) - 4.f * (c - m_sq * a);
        T[row] = mu - ZTH * sqrtf(fmaxf(var, 0.f));
    }
}

// ---------------- K6: fused split-bf16 MFMA distance + threshold push ----------------
__global__ __launch_bounds__(256, 2) void k_fused(
        const unsigned short* __restrict__ Xhi, const unsigned short* __restrict__ Xlo,
        const float* __restrict__ sqn, const float* __restrict__ T,
        unsigned long long* __restrict__ list, int* __restrict__ cntg) {
    __shared__ uint4 sBhi[64 * 16];
    __shared__ uint4 sBlo[64 * 16];

    const int t    = threadIdx.x;
    const int lane = t & 63;
    const int w    = t >> 6;
    const int lrow = lane & 15;
    const int lkg  = lane >> 4;

    const int rbase    = blockIdx.y * 64;
    const int colbase0 = blockIdx.x * 2048;

    short8 ahi[4][4], alo[4][4];
    #pragma unroll
    for (int i = 0; i < 4; ++i)
        #pragma unroll
        for (int kc = 0; kc < 4; ++kc) {
            size_t g = (size_t)(rbase + (i << 4) + lrow) * 128 + kc * 32 + lkg * 8;
            ahi[i][kc] = *(const short8*)&Xhi[g];
            alo[i][kc] = *(const short8*)&Xlo[g];
        }
    float sa[4][4], Ta[4][4];
    #pragma unroll
    for (int i = 0; i < 4; ++i)
        #pragma unroll
        for (int q = 0; q < 4; ++q) {
            int r = rbase + (i << 4) + (lkg << 2) + q;
            sa[i][q] = sqn[r];
            Ta[i][q] = T[r];
        }

    for (int it = 0; it < 32; ++it) {
        const int colbase = colbase0 + it * 64;
        __syncthreads();
        #pragma unroll
        for (int p = 0; p < 4; ++p) {
            int u = t + 256 * p, r = u >> 4, c = u & 15;
            int phys = r * 16 + (c ^ (r & 7));
            size_t g = (size_t)(colbase + r) * 128 + c * 8;
            sBhi[phys] = *(const uint4*)&Xhi[g];
            sBlo[phys] = *(const uint4*)&Xlo[g];
        }
        __syncthreads();

        const int jj = (w << 4) | lrow;
        short8 bhi[4], blo[4];
        #pragma unroll
        for (int kc = 0; kc < 4; ++kc) {
            int phys = jj * 16 + ((kc * 4 + lkg) ^ (jj & 7));
            bhi[kc] = *(const short8*)&sBhi[phys];
            blo[kc] = *(const short8*)&sBlo[phys];
        }

        f32x4 acc[4];
        #pragma unroll
        for (int i = 0; i < 4; ++i) acc[i] = (f32x4){0.f, 0.f, 0.f, 0.f};
        #pragma unroll
        for (int kc = 0; kc < 4; ++kc)
            #pragma unroll
            for (int i = 0; i < 4; ++i) {
                acc[i] = __builtin_amdgcn_mfma_f32_16x16x32_bf16(ahi[i][kc], bhi[kc], acc[i], 0, 0, 0);
                acc[i] = __builtin_amdgcn_mfma_f32_16x16x32_bf16(ahi[i][kc], blo[kc], acc[i], 0, 0, 0);
                acc[i] = __builtin_amdgcn_mfma_f32_16x16x32_bf16(alo[i][kc], bhi[kc], acc[i], 0, 0, 0);
            }

        const int cola = colbase + (w << 4) + lrow;
        const float sb = sqn[cola];
        #pragma unroll
        for (int i = 0; i < 4; ++i)
            #pragma unroll
            for (int q = 0; q < 4; ++q) {
                float d2v = fmaxf(fmaf(-2.f, acc[i][q], sa[i][q] + sb), 0.f);
                if (d2v < Ta[i][q]) {
                    int grow = rbase + (i << 4) + (lkg << 2) + q;
                    int pos = atomicAdd(&cntg[grow], 1);
                    if (pos < LCAP)
                        list[(size_t)grow * LCAP + pos] =
                            ((unsigned long long)__float_as_uint(d2v) << 14) |
                            (unsigned long long)(cola + 1);
                }
            }
    }
}

// ---------------- K7: exact top-20 from candidate list; compact bad rows ----------
__global__ void k_top(const unsigned long long* __restrict__ list,
                      const int* __restrict__ cntg, int* __restrict__ knn_idx,
                      float* __restrict__ density, int* __restrict__ flagcnt,
                      int* __restrict__ flaglist) {
    int row = blockIdx.x, t = threadIdx.x;
    int cnt = cntg[row];
    bool bad = (cnt < KNN) || (cnt > LCAP);
    if (bad) {
        if (t == 0) {
            int p = atomicAdd(flagcnt, 1);       // flaglist sized N: no overflow
            flaglist[p] = row;
        }
        return;
    }
    const unsigned long long* Lp = list + (size_t)row * LCAP;
    unsigned long long last = 0ull;
    float sumd = 0.f;
    for (int r = 0; r < KNN; ++r) {
        unsigned long long m = ~0ull;
        for (int s = t; s < cnt; s += 64) {
            unsigned long long k = Lp[s];
            if (k > last && k < m) m = k;
        }
        #pragma unroll
        for (int off = 32; off; off >>= 1) {
            unsigned long long o = __shfl_down(m, off, 64);
            if (o < m) m = o;
        }
        m = __shfl(m, 0, 64);
        last = m;
        if (t == 0) {
            int j = (int)(m & 16383ull) - 1;
            if (j < 0) j = 0; if (j >= N) j = N - 1;
            knn_idx[(size_t)row * KNN + r] = j;
            sumd += sqrtf(__uint_as_float((unsigned)(m >> 14)));
        }
    }
    if (t == 0) density[row] = 1.f / (sumd * (1.f / KNN) + EPS);
}

// ---------------- K8: parallel exact d2 for flagged rows (32 blocks/row) ----------
__global__ void k_fbdist(const float* __restrict__ X, const float* __restrict__ sqn,
                         const int* __restrict__ flagcnt, const int* __restrict__ flaglist,
                         float* __restrict__ d2fb) {
    int fc = *flagcnt; if (fc > FBMAX) fc = FBMAX;
    int j = blockIdx.x * 256 + threadIdx.x;
    const float4* xj4 = (const float4*)X + (size_t)j * 32;
    for (int ry = blockIdx.y; ry < fc; ry += 64) {
        int row = flaglist[ry];
        const float4* xi4 = (const float4*)X + (size_t)row * 32;
        float dot = 0.f;
        #pragma unroll
        for (int d4 = 0; d4 < 32; ++d4) {
            float4 a = xj4[d4];
            float4 b = xi4[d4];                  // broadcast across threads
            dot = fmaf(a.x, b.x, dot); dot = fmaf(a.y, b.y, dot);
            dot = fmaf(a.z, b.z, dot); dot = fmaf(a.w, b.w, dot);
        }
        d2fb[(size_t)ry * N + j] = fmaxf(sqn[row] + sqn[j] - 2.f * dot, 0.f);
    }
}

// ---------------- K9: exact select for flagged rows (grid-stride, 64 blocks) ----
__global__ __launch_bounds__(256) void k_fbsel(const float* __restrict__ d2fb,
        const float* __restrict__ X, const float* __restrict__ sqn,
        const int* __restrict__ flagcnt, const int* __restrict__ flaglist,
        int* __restrict__ knn_idx, float* __restrict__ density) {
    __shared__ float redf1[256], redf2[256];
    __shared__ int redi[256];
    __shared__ unsigned long long lst[2048];
    __shared__ int lc;
    int t = threadIdx.x;
    int fc = *flagcnt;
    for (int ry = blockIdx.x; ry < fc; ry += 64) {
        int row = flaglist[ry];
        float v[32];
        if (ry < FBMAX) {
            const float4* rp = (const float4*)(d2fb + (size_t)ry * N);
            #pragma unroll
            for (int p = 0; p < 8; ++p) {
                float4 g = rp[t + 256 * p];
                v[4 * p + 0] = g.x; v[4 * p + 1] = g.y; v[4 * p + 2] = g.z; v[4 * p + 3] = g.w;
            }
        } else {                                 // overflow slow path (never expected)
            const float4* xi4 = (const float4*)X + (size_t)row * 32;
            float sqi = sqn[row];
            #pragma unroll
            for (int i = 0; i < 32; ++i) {
                int j = 4 * (t + 256 * (i >> 2)) + (i & 3);
                const float4* xj4 = (const float4*)X + (size_t)j * 32;
                float dot = 0.f;
                for (int d4 = 0; d4 < 32; ++d4) {
                    float4 a = xj4[d4], b = xi4[d4];
                    dot = fmaf(a.x, b.x, dot); dot = fmaf(a.y, b.y, dot);
                    dot = fmaf(a.z, b.z, dot); dot = fmaf(a.w, b.w, dot);
                }
                v[i] = fmaxf(sqi + sqn[j] - 2.f * dot, 0.f);
            }
        }

        float s1 = 0.f, s2 = 0.f;
        #pragma unroll
        for (int i = 0; i < 32; ++i) { s1 += v[i]; s2 = fmaf(v[i], v[i], s2); }
        redf1[t] = s1; redf2[t] = s2; __syncthreads();
        for (int sft = 128; sft; sft >>= 1) {
            if (t < sft) { redf1[t] += redf1[t + sft]; redf2[t] += redf2[t + sft]; }
            __syncthreads();
        }
        float mu = redf1[0] * (1.f / N);
        float var = redf2[0] * (1.f / N) - mu * mu;
        float sigma = sqrtf(fmaxf(var, 0.f)) + 1e-6f;
        __syncthreads();

        float Tlo = 0.f, Thi = mu, T = mu - 2.2f * sigma;
        if (T <= 0.f) T = 0.5f * (Tlo + Thi);
        for (int it = 0; it < 32; ++it) {
            int c = 0;
            #pragma unroll
            for (int i = 0; i < 32; ++i) c += (v[i] < T) ? 1 : 0;
            redi[t] = c; __syncthreads();
            for (int sft = 128; sft; sft >>= 1) {
                if (t < sft) redi[t] += redi[t + sft];
                __syncthreads();
            }
            int n = redi[0]; __syncthreads();
            if (n >= KNN && n <= 2048) break;
            if (n < KNN) Tlo = T; else Thi = T;
            T = 0.5f * (Tlo + Thi);
        }

        if (t == 0) lc = 0;
        __syncthreads();
        #pragma unroll
        for (int i = 0; i < 32; ++i) {
            if (v[i] < T) {
                int pos = atomicAdd(&lc, 1);
                if (pos < 2048) {
                    int j = 4 * (t + 256 * (i >> 2)) + (i & 3);
                    lst[pos] = ((unsigned long long)__float_as_uint(v[i]) << 14) |
                               (unsigned long long)(j + 1);
                }
            }
        }
        __syncthreads();
        int n = min(lc, 2048);
        if (t < 64) {
            unsigned long long last = 0ull; float sumd = 0.f;
            for (int r = 0; r < KNN; ++r) {
                unsigned long long m = ~0ull;
                for (int s = t; s < n; s += 64) {
                    unsigned long long k = lst[s];
                    if (k > last && k < m) m = k;
                }
                #pragma unroll
                for (int off = 32; off; off >>= 1) {
                    unsigned long long o = __shfl_down(m, off, 64);
                    if (o < m) m = o;
                }
                m = __shfl(m, 0, 64);
                last = m;
                if (t == 0) {
                    int j = (int)(m & 16383ull) - 1;
                    if (j < 0) j = 0; if (j >= N) j = N - 1;
                    knn_idx[(size_t)row * KNN + r] = j;
                    sumd += sqrtf(__uint_as_float((unsigned)(m >> 14)));
                }
            }
            if (t == 0) density[row] = 1.f / (sumd * (1.f / KNN) + EPS);
        }
        __syncthreads();                         // protect shared reuse next ry
    }
}

// ---------------- K10: scatter knn + rnn (deduped) contributions ----------------
__global__ void k_scatter(const int* __restrict__ knn_idx, const float* __restrict__ density,
                          float* __restrict__ numer, float* __restrict__ cnt) {
    int p = blockIdx.x * 256 + threadIdx.x;
    if (p >= N * KNN) return;
    int i = p / KNN;
    int j = knn_idx[p];
    atomicAdd(&numer[i], density[j]);
    atomicAdd(&cnt[i], 1.f);
    bool found = false;
    const int* kj = knn_idx + (size_t)j * KNN;
    #pragma unroll
    for (int m = 0; m < KNN; ++m) found |= (kj[m] == i);
    if (!found) {
        atomicAdd(&numer[j], density[i]);
        atomicAdd(&cnt[j], 1.f);
    }
}

// ---------------- K11: scores, flags, class preds ----------------
__global__ void k_final(const float* __restrict__ density, const float* __restrict__ numer,
                        const float* __restrict__ cnt, const float* __restrict__ logits,
                        float* __restrict__ out) {
    int i = blockIdx.x * 256 + threadIdx.x;
    if (i >= N) return;
    float c     = fmaxf(cnt[i], 1.f);
    float avg   = numer[i] / c;
    float score = -(density[i] / (avg + EPS));
    out[i] = score;
    bool flag = score < -0.5f;
    out[N + i] = flag ? 1.f : 0.f;
    const float* lg = logits + (size_t)i * NC;
    float best = lg[0]; int bi = 0;
    #pragma unroll
    for (int k = 1; k < NC; ++k) { float x = lg[k]; if (x > best) { best = x; bi = k; } }
    out[2 * N + i] = flag ? -1.f : (float)bi;
}

extern "C" void kernel_launch(void* const* d_in, const int* in_sizes, int n_in,
                              void* d_out, int out_size, void* d_ws, size_t ws_size,
                              hipStream_t stream) {
    const float* X      = (const float*)d_in[0];
    const float* logits = (const float*)d_in[1];
    float* out = (float*)d_out;

    char* w = (char*)d_ws;
    auto alloc = [&](size_t bytes) { char* p = w; w += (bytes + 255) & ~(size_t)255; return p; };
    float* sq      = (float*)alloc((size_t)N * 4);
    float* T       = (float*)alloc((size_t)N * 4);
    float* density = (float*)alloc((size_t)N * 4);
    int*   knn     = (int*)alloc((size_t)N * KNN * 4);
    int*   flaglist= (int*)alloc((size_t)N * 4);
    // ---- contiguous zero block (single memset) ----
    char*  zero0   = w;
    float* numer   = (float*)alloc((size_t)N * 4);
    float* cntb    = (float*)alloc((size_t)N * 4);
    int*   cntg    = (int*)alloc((size_t)N * 4);
    float* xbsum   = (float*)alloc(512);
    float* wvsum   = (float*)alloc(512);
    float* scal_s  = (float*)alloc(256);
    int*   flagcnt = (int*)alloc(256);
    size_t zbytes  = (size_t)(w - zero0);
    // ---- end zero block ----
    unsigned short* Xhi = (unsigned short*)alloc((size_t)N * D * 2);
    unsigned short* Xlo = (unsigned short*)alloc((size_t)N * D * 2);
    float* M       = (float*)alloc(65536);
    float* Mpart   = (float*)alloc((size_t)128 * 16384 * 4);
    float* Y       = (float*)alloc((size_t)N * 128 * 4);
    float* d2fb    = (float*)alloc((size_t)FBMAX * N * 4);
    unsigned long long* list = (unsigned long long*)alloc((size_t)N * LCAP * 8);

    (void)hipMemsetAsync(zero0, 0, zbytes, stream);

    k_sqsplit <<<N, 64, 0, stream>>>(X, sq, Xhi, Xlo);
    k_colstats<<<64, 256, 0, stream>>>(X, sq, xbsum, wvsum, scal_s);
    k_Mpart   <<<128, 256, 0, stream>>>(X, Mpart);
    k_Mred    <<<64, 256, 0, stream>>>(Mpart, M);
    k_gemmY   <<<dim3(2, 128), 256, 0, stream>>>(X, M, Y);
    k_thresh  <<<N / 4, 256, 0, stream>>>(X, Y, sq, xbsum, wvsum, scal_s, T);
    k_fused   <<<dim3(4, 128), 256, 0, stream>>>(Xhi, Xlo, sq, T, list, cntg);
    k_top     <<<N, 64, 0, stream>>>(list, cntg, knn, density, flagcnt, flaglist);
    k_fbdist  <<<dim3(32, 64), 256, 0, stream>>>(X, sq, flagcnt, flaglist, d2fb);
    k_fbsel   <<<64, 256, 0, stream>>>(d2fb, X, sq, flagcnt, flaglist, knn, density);
    k_scatter <<<(N * KNN + 255) / 256, 256, 0, stream>>>(knn, density, numer, cntb);
    k_final   <<<(N + 255) / 256, 256, 0, stream>>>(density, numer, cntb, logits, out);
}